// Round 8
// baseline (118.526 us; speedup 1.0000x reference)
//
#include <hip/hip_runtime.h>
#include <hip/hip_bf16.h>
#include <math.h>
#include <stdint.h>

#define N_ATOMS 512
#define NF 64
#define NB 8
#define NBINS 64
#define NSEG 511     // segment nodes 0..510; valid pairs i<j, j>=i+2
#define NTF 8192     // fine m(wr) grid (nearest; bf16; sentinel row = NTF)
#define NSENT 2554   // invalid (dst,src) slots per batch needing the zero-sentinel
#define ETILES2 254  // ceil(P/512) edge tiles per batch (2 edges/thread)

__device__ __forceinline__ float dot3(float ax, float ay, float az,
                                      float bx, float by, float bz) {
    return fmaf(ax, bx, fmaf(ay, by, az * bz));
}

__device__ __forceinline__ uint16_t bf16_bits(float f) {
    union { __hip_bfloat16 h; uint16_t u; } cv;
    cv.h = __float2bfloat16(f);
    return cv.u;
}

// writhe scalar for edge (i,j), i<j — verified (R2..R15 absmax 0.0625).
// pb may point to LDS (generic pointer) — xyz layout [atom][3].
__device__ __forceinline__ float compute_wr(const float* pb, int i, int j) {
    float p0x = pb[3*i+0], p0y = pb[3*i+1], p0z = pb[3*i+2];
    float p1x = pb[3*i+3], p1y = pb[3*i+4], p1z = pb[3*i+5];
    float p2x = pb[3*j+0], p2y = pb[3*j+1], p2z = pb[3*j+2];
    float p3x = pb[3*j+3], p3y = pb[3*j+4], p3z = pb[3*j+5];

    float d0x = p2x-p0x, d0y = p2y-p0y, d0z = p2z-p0z;
    float d1x = p3x-p0x, d1y = p3y-p0y, d1z = p3z-p0z;
    float d2x = p2x-p1x, d2y = p2y-p1y, d2z = p2z-p1z;
    float d3x = p3x-p1x, d3y = p3y-p1y, d3z = p3z-p1z;
    {
        float n0 = rsqrtf(dot3(d0x,d0y,d0z,d0x,d0y,d0z)); d0x*=n0; d0y*=n0; d0z*=n0;
        float n1 = rsqrtf(dot3(d1x,d1y,d1z,d1x,d1y,d1z)); d1x*=n1; d1y*=n1; d1z*=n1;
        float n2 = rsqrtf(dot3(d2x,d2y,d2z,d2x,d2y,d2z)); d2x*=n2; d2y*=n2; d2z*=n2;
        float n3 = rsqrtf(dot3(d3x,d3y,d3z,d3x,d3y,d3z)); d3x*=n3; d3y*=n3; d3z*=n3;
    }
    float c0x = d0y*d1z - d0z*d1y, c0y = d0z*d1x - d0x*d1z, c0z = d0x*d1y - d0y*d1x;
    float c1x = d1y*d3z - d1z*d3y, c1y = d1z*d3x - d1x*d3z, c1z = d1x*d3y - d1y*d3x;
    float c3x = d2y*d0z - d2z*d0y, c3y = d2z*d0x - d2x*d0z, c3z = d2x*d0y - d2y*d0x;
    {
        float n0 = rsqrtf(dot3(c0x,c0y,c0z,c0x,c0y,c0z)); c0x*=n0; c0y*=n0; c0z*=n0;
        float n1 = rsqrtf(dot3(c1x,c1y,c1z,c1x,c1y,c1z)); c1x*=n1; c1y*=n1; c1z*=n1;
        float n3 = rsqrtf(dot3(c3x,c3y,c3z,c3x,c3y,c3z)); c3x*=n3; c3y*=n3; c3z*=n3;
    }
    float t0 = fminf(fmaxf(dot3(c0x,c0y,c0z, c1x,c1y,c1z), -1.f), 1.f);
    float t1 = fminf(fmaxf(dot3(c1x,c1y,c1z, c3x,c3y,c3z), -1.f), 1.f);
    float t3 = fminf(fmaxf(dot3(c3x,c3y,c3z, c0x,c0y,c0z), -1.f), 1.f);
    float omega = asinf(t0) + asinf(t1) + asinf(t3) + 1.5707963267948966f;
    float ex = p3x-p2x, ey = p3y-p2y, ez = p3z-p2z;
    float fx = p1x-p0x, fy = p1y-p0y, fz = p1z-p0z;
    float gx = ey*fz - ez*fy, gy = ez*fx - ex*fz, gz = ex*fy - ey*fx;
    float sgd = dot3(gx,gy,gz, d0x,d0y,d0z);
    float sgn = (sgd > 0.f) ? 1.f : ((sgd < 0.f) ? -1.f : 0.f);
    return omega * sgn * 0.15915494309189535f;
}

// map wr -> pre-shifted nearest table element offset (proven R13..R15)
__device__ __forceinline__ uint32_t wr_to_off(float w) {
    float tf = (w + 1.0f) * ((float)(NTF - 1) * 0.5f);
    tf = fminf(fmaxf(tf, 0.0f), (float)(NTF - 1));
    int t0 = (int)(tf + 0.5f);
    t0 = (t0 > NTF - 1) ? (NTF - 1) : t0;
    return (uint32_t)t0 << 6;
}

// ---------------- launch 1: mega-prepass (R5 structure, proven) -----------------
// block ranges: [0,1024) table build (2 pts/wave) | [+2032) edge writhes
//   (xyz in LDS, 2 edges/thread) | next 80 sentinel fill.
__launch_bounds__(256)
__global__ void prepass(
        const float* __restrict__ xyz, const int* __restrict__ seg,
        const float* __restrict__ W1, const float* __restrict__ b1,
        const float* __restrict__ W2, const float* __restrict__ b2,
        uint16_t* __restrict__ tabh, uint32_t* __restrict__ ta, int P) {
    __shared__ float lds[1536];   // build: 2x lh[4][64]; edge: xyz[b] (6 KB)

    const unsigned bx = blockIdx.x;

    if (bx < NTF / 8) {
        // ------- bf16 fine-table build: wave handles g and g+NTF/2 (ILP x2) -----
        const int widx = threadIdx.x >> 6;
        const int lane = threadIdx.x & 63;
        const int g = bx * 4 + widx;              // 0..4095
        const int g2 = g + NTF / 2;               // 4096..8191

        float tta = ((-1.0f + (2.0f / (float)(NTF - 1)) * (float)g)  + 1.0f) * 31.5f;
        float ttb = ((-1.0f + (2.0f / (float)(NTF - 1)) * (float)g2) + 1.0f) * 31.5f;

        float a0=0.f,a1=0.f,a2=0.f,a3=0.f, e0=0.f,e1=0.f,e2=0.f,e3=0.f;
        #pragma unroll
        for (int k = 0; k < NBINS; k += 4) {
            #pragma unroll
            for (int q = 0; q < 4; ++q) {
                float da = tta - (float)(k + q);
                float db = ttb - (float)(k + q);
                float ra = __expf(-da * da) * 0.8928571428571429f;
                float rb = __expf(-db * db) * 0.8928571428571429f;
                float wv = W1[(k + q) * NF + lane];
                if (q == 0) { a0 = fmaf(ra, wv, a0); e0 = fmaf(rb, wv, e0); }
                if (q == 1) { a1 = fmaf(ra, wv, a1); e1 = fmaf(rb, wv, e1); }
                if (q == 2) { a2 = fmaf(ra, wv, a2); e2 = fmaf(rb, wv, e2); }
                if (q == 3) { a3 = fmaf(ra, wv, a3); e3 = fmaf(rb, wv, e3); }
            }
        }
        float ha = ((a0 + a1) + (a2 + a3)) + b1[lane];
        float hb = ((e0 + e1) + (e2 + e3)) + b1[lane];
        ha = fmaxf(ha, 0.01f * ha);
        hb = fmaxf(hb, 0.01f * hb);
        lds[widx * 64 + lane]       = ha;
        lds[256 + widx * 64 + lane] = hb;
        __syncthreads();

        float m0=0.f,m1=0.f,m2=0.f,m3=0.f, n0=0.f,n1=0.f,n2=0.f,n3=0.f;
        #pragma unroll
        for (int k = 0; k < NF; k += 4) {
            float w0 = W2[(k + 0) * NF + lane];
            float w1v = W2[(k + 1) * NF + lane];
            float w2v = W2[(k + 2) * NF + lane];
            float w3 = W2[(k + 3) * NF + lane];
            m0 = fmaf(lds[widx * 64 + k + 0], w0, m0);
            m1 = fmaf(lds[widx * 64 + k + 1], w1v, m1);
            m2 = fmaf(lds[widx * 64 + k + 2], w2v, m2);
            m3 = fmaf(lds[widx * 64 + k + 3], w3, m3);
            n0 = fmaf(lds[256 + widx * 64 + k + 0], w0, n0);
            n1 = fmaf(lds[256 + widx * 64 + k + 1], w1v, n1);
            n2 = fmaf(lds[256 + widx * 64 + k + 2], w2v, n2);
            n3 = fmaf(lds[256 + widx * 64 + k + 3], w3, n3);
        }
        float ma = ((m0 + m1) + (m2 + m3)) + b2[lane];
        float mb = ((n0 + n1) + (n2 + n3)) + b2[lane];
        tabh[g  * NF + lane] = bf16_bits(ma);
        tabh[g2 * NF + lane] = bf16_bits(mb);
        if (g == 0) tabh[NTF * NF + lane] = 0;     // sentinel zero row
    } else if (bx < NTF / 8 + NB * ETILES2) {
        // ------- edge writhes, xyz[b] in LDS, 2 independent edges/thread --------
        const int rel = bx - NTF / 8;
        const int b = rel / ETILES2;
        const int tile = rel - b * ETILES2;

        const float* xb = xyz + b * (N_ATOMS * 3);
        #pragma unroll
        for (int k = 0; k < 6; ++k)
            lds[k * 256 + threadIdx.x] = xb[k * 256 + threadIdx.x];
        __syncthreads();

        #pragma unroll
        for (int q = 0; q < 2; ++q) {
            const int e = tile * 512 + q * 256 + threadIdx.x;
            if (e < P) {
                int4 sv = ((const int4*)seg)[e];
                const int i = sv.x;
                const int j = sv.z;
                uint32_t u = wr_to_off(compute_wr(lds, i, j));
                ta[(b << 18) + (i << 9) + j] = u;
                ta[(b << 18) + (j << 9) + i] = u;   // mirror (m symmetric)
            }
        }
    } else {
        // ------- sentinel fill --------------------------------------------------
        const int idx = (bx - (NTF / 8 + NB * ETILES2)) * 256 + threadIdx.x;
        if (idx < NB * NSENT) {
            const int b = idx / NSENT;
            const int k = idx - b * NSENT;
            int d, s;
            if      (k < 512)  { d = k;        s = k;     }   // diagonal
            else if (k < 1023) { d = k - 512;  s = d + 1; }   // upper band
            else if (k < 1534) { s = k - 1023; d = s + 1; }   // lower band
            else if (k < 2044) { d = k - 1534; s = NSEG;  }   // col 511 (d<=509)
            else               { s = k - 2044; d = NSEG;  }   // row 511 (s<=509)
            ta[(b << 18) + (d << 9) + s] = (uint32_t)NTF << 6;  // -> zero row
        }
    }
}

// ---------------- launch 2: aggregation v17 — barrier-free L2 gather ------------
// R7 evidence: agg16's profiled dispatch showed 3.7% occupancy / 3.6% VALUBusy
// (idle-wait, not issue-bound); 3 structures converged at ~27us. Common factor:
// per-chunk __syncthreads + LDS staging serializing all 16 waves around the
// gather 4x per kernel. agg17 removes it: x[b] is L2-resident (128 KB, reused
// by 64 blocks/batch) -> read x DIRECTLY from L2 with static per-lane addresses
// (1 KB/instr coalesced, hoistable); preload the wave's half-row of ta offsets
// (4 coalesced dwords) upfront; row-select via one ds_bpermute (__shfl) per
// 4-src group. Main loop = pure independent {shfl -> gather dwordx2} || {static
// x float4} -> 4 fma; NO barriers until the single half-combine (2 KB LDS).
// Quad-pack layout identical to agg16 (proven numerics): lane = (rw, fl),
// features 4fl..4fl+3, srcs 4g+rw; rw-reduce via 2 shfl_xor.
__launch_bounds__(1024, 8)
__global__ void agg17(
        const float* __restrict__ x, const uint32_t* __restrict__ ta,
        const uint16_t* __restrict__ tabh, float* __restrict__ out) {
    __shared__ float xs[512];   // 8 dst x 64 feat combine buffer (h=1 partials)

    const int tid  = threadIdx.x;
    const int widx = tid >> 6;               // 0..15
    const int lane = tid & 63;
    const int fl   = lane & 15;              // feature quad: features 4fl..4fl+3
    const int rw   = lane >> 4;              // src slot (0..3) within group
    const int h    = widx >> 3;              // half-row: srcs h*256 .. h*256+255
    const int r    = widx & 7;               // dst row within block
    const int bid  = blockIdx.x;             // 0..511
    const int b    = bid >> 6;
    const int dst  = ((bid & 63) << 3) + r;  // 0..511
    const int feidx = fl << 2;

    // preload this wave's half-row of table offsets (4 coalesced dwords)
    const uint32_t* tarow =
        ta + ((size_t)b << 18) + ((size_t)dst << 9) + (h << 8);
    const int tv0 = (int)tarow[lane];
    const int tv1 = (int)tarow[64 + lane];
    const int tv2 = (int)tarow[128 + lane];
    const int tv3 = (int)tarow[192 + lane];

    // static per-lane x base: batch b, src block h*256, slot rw, feature quad
    const float* xb = x + ((size_t)b << 15);
    const float* xh = xb + (h << 14) + (rw << 6) + feidx;

    float acc0 = 0.f, acc1 = 0.f, acc2 = 0.f, acc3 = 0.f;
    #pragma unroll
    for (int cc = 0; cc < 4; ++cc) {
        const int tvc = (cc == 0) ? tv0 : (cc == 1) ? tv1 : (cc == 2) ? tv2 : tv3;
        const float* xc = xh + (cc << 12);
        #pragma unroll
        for (int g4 = 0; g4 < 16; g4 += 4) {
            // ---- issue 4 independent {row-select + gather} and 4 static x loads
            uint2  mw[4];
            float4 xv[4];
            #pragma unroll
            for (int q = 0; q < 4; ++q) {
                const int gg = g4 + q;
                const int osel = __shfl(tvc, 4 * gg + rw);   // ds_bpermute
                mw[q] = *(const uint2*)(tabh + osel + feidx);
                xv[q] = *(const float4*)(xc + (gg << 8));
            }
            // ---- consume: unpack 4 bf16 + 4 fma --------------------------------
            #pragma unroll
            for (int q = 0; q < 4; ++q) {
                acc0 = fmaf(__uint_as_float(mw[q].x << 16),          xv[q].x, acc0);
                acc1 = fmaf(__uint_as_float(mw[q].x & 0xffff0000u),  xv[q].y, acc1);
                acc2 = fmaf(__uint_as_float(mw[q].y << 16),          xv[q].z, acc2);
                acc3 = fmaf(__uint_as_float(mw[q].y & 0xffff0000u),  xv[q].w, acc3);
            }
        }
    }
    // reduce over the 4 rw-groups (lanes fl, fl+16, fl+32, fl+48)
    acc0 += __shfl_xor(acc0, 16); acc0 += __shfl_xor(acc0, 32);
    acc1 += __shfl_xor(acc1, 16); acc1 += __shfl_xor(acc1, 32);
    acc2 += __shfl_xor(acc2, 16); acc2 += __shfl_xor(acc2, 32);
    acc3 += __shfl_xor(acc3, 16); acc3 += __shfl_xor(acc3, 32);

    // combine halves: h=1 publishes partial, one barrier, h=0 adds and stores
    if (h == 1 && rw == 0) {
        float4 v; v.x = acc0; v.y = acc1; v.z = acc2; v.w = acc3;
        *(float4*)&xs[(r << 6) + feidx] = v;
    }
    __syncthreads();
    if (h == 0 && rw == 0) {
        const float4 prev = *(const float4*)&xs[(r << 6) + feidx];
        const float4 xv   = *(const float4*)(xb + (dst << 6) + feidx);
        float4 res;
        res.x = xv.x + acc0 + prev.x;
        res.y = xv.y + acc1 + prev.y;
        res.z = xv.z + acc2 + prev.z;
        res.w = xv.w + acc3 + prev.w;
        *(float4*)(out + ((size_t)b << 15) + (dst << 6) + feidx) = res;
    }
}

// ---------------- fallback path (ws too small): R2 atomic kernel (proven) -------

__global__ void init_out_kernel(const float* __restrict__ x, float* __restrict__ out, int n) {
    int idx = blockIdx.x * blockDim.x + threadIdx.x;
    if (idx < n) out[idx] = x[idx];
}

__device__ __forceinline__ void compute_m(
        const float* __restrict__ pb, int i, int j,
        const float* __restrict__ W1, const float* __restrict__ b1,
        const float* __restrict__ W2, const float* __restrict__ b2,
        float* __restrict__ mout) {
    float wr = compute_wr(pb, i, j);
    float acc_[NBINS];
    {
        float tt = (wr + 1.0f) * 31.5f;
        #pragma unroll
        for (int k = 0; k < NBINS; ++k) {
            float d = tt - (float)k;
            acc_[k] = __expf(-d * d) * 0.8928571428571429f;
        }
    }
    float h_[NF];
    #pragma unroll
    for (int f = 0; f < NF; ++f) h_[f] = b1[f];
    #pragma unroll
    for (int k = 0; k < NBINS; ++k) {
        float r = acc_[k];
        #pragma unroll
        for (int f = 0; f < NF; ++f) h_[f] = fmaf(r, W1[k * NF + f], h_[f]);
    }
    #pragma unroll
    for (int f = 0; f < NF; ++f) h_[f] = fmaxf(h_[f], 0.01f * h_[f]);
    #pragma unroll
    for (int f = 0; f < NF; ++f) acc_[f] = b2[f];
    #pragma unroll
    for (int k = 0; k < NF; ++k) {
        float hk = h_[k];
        #pragma unroll
        for (int f = 0; f < NF; ++f) acc_[f] = fmaf(hk, W2[k * NF + f], acc_[f]);
    }
    #pragma unroll
    for (int f = 0; f < NF; ++f) mout[f] = acc_[f];
}

__launch_bounds__(256, 2)
__global__ void writhe_msg_atomic_kernel(
        const float* __restrict__ x, const float* __restrict__ xyz,
        const int* __restrict__ seg,
        const float* __restrict__ W1, const float* __restrict__ b1,
        const float* __restrict__ W2, const float* __restrict__ b2,
        float* __restrict__ out, int P, int n_tiles) {
    __shared__ __hip_bfloat16 lds_m[4][64 * 65];
    __shared__ int lds_i[4][64];
    __shared__ int lds_j[4][64];

    const int widx = threadIdx.x >> 6;
    const int lane = threadIdx.x & 63;
    const int wave_g = blockIdx.x * 4 + widx;
    const int b = wave_g / n_tiles;
    const int tile = wave_g - b * n_tiles;
    const int bc = (b < NB) ? b : 0;
    const int e = tile * 64 + lane;
    const bool valid = (b < NB) && (e < P);

    int4 sv = valid ? ((const int4*)seg)[e] : make_int4(0, 1, 2, 3);
    const int i = sv.x;
    const int j = sv.z;

    float m[NF];
    compute_m(xyz + bc * (N_ATOMS * 3), i, j, W1, b1, W2, b2, m);

    const float scale = valid ? 1.0f : 0.0f;
    #pragma unroll
    for (int f = 0; f < NF; ++f)
        lds_m[widx][lane * 65 + f] = __float2bfloat16(m[f] * scale);
    lds_i[widx][lane] = i;
    lds_j[widx][lane] = j;
    __syncthreads();

    const float* xb = x + bc * (N_ATOMS * NF);
    float* ob = out + bc * (N_ATOMS * NF);
    int cur_i = lds_i[widx][0];
    float acc_i = 0.0f;
    for (int ee = 0; ee < 64; ++ee) {
        int ie = lds_i[widx][ee];
        int je = lds_j[widx][ee];
        float mv = __bfloat162float(lds_m[widx][ee * 65 + lane]);
        float xi = xb[ie * NF + lane];
        float xj = xb[je * NF + lane];
        atomicAdd(&ob[je * NF + lane], mv * xi);
        if (ie != cur_i) {
            atomicAdd(&ob[cur_i * NF + lane], acc_i);
            acc_i = 0.0f;
            cur_i = ie;
        }
        acc_i = fmaf(mv, xj, acc_i);
    }
    atomicAdd(&ob[cur_i * NF + lane], acc_i);
}

extern "C" void kernel_launch(void* const* d_in, const int* in_sizes, int n_in,
                              void* d_out, int out_size, void* d_ws, size_t ws_size,
                              hipStream_t stream) {
    const float* x   = (const float*)d_in[0];
    const float* xyz = (const float*)d_in[1];
    const int*   seg = (const int*)d_in[2];
    const float* W1  = (const float*)d_in[3];
    const float* b1  = (const float*)d_in[4];
    const float* W2  = (const float*)d_in[5];
    const float* b2  = (const float*)d_in[6];
    float* out = (float*)d_out;

    const int P = in_sizes[2] / 4;              // 129795 edges
    const int n_tiles = (P + 63) / 64;          // 2029

    const size_t tabh_bytes = (size_t)(NTF + 1) * NF * sizeof(uint16_t);         // 1.05 MB
    const size_t ta_bytes   = (size_t)NB * N_ATOMS * N_ATOMS * sizeof(uint32_t); // 8 MB
    const size_t need_ws = tabh_bytes + ta_bytes;

    if (ws_size >= need_ws && P <= ETILES2 * 512) {
        uint16_t* tabh = (uint16_t*)d_ws;
        uint32_t* ta   = (uint32_t*)((char*)d_ws + tabh_bytes);

        const int nsent_blocks = (NB * NSENT + 255) / 256;            // 80
        const int total_blocks = NTF / 8 + NB * ETILES2 + nsent_blocks;
        hipLaunchKernelGGL(prepass, dim3(total_blocks), dim3(256), 0, stream,
                           xyz, seg, W1, b1, W2, b2, tabh, ta, P);

        hipLaunchKernelGGL(agg17, dim3(NB * 64), dim3(1024), 0, stream,
                           x, ta, tabh, out);
    } else {
        const int n = out_size;
        hipLaunchKernelGGL(init_out_kernel, dim3((n + 255) / 256), dim3(256), 0, stream,
                           x, out, n);
        const int total_waves = NB * n_tiles;
        const int blocks = (total_waves + 3) / 4;
        hipLaunchKernelGGL(writhe_msg_atomic_kernel, dim3(blocks), dim3(256), 0, stream,
                           x, xyz, seg, W1, b1, W2, b2, out, P, n_tiles);
    }
}

// Round 9
// 107.491 us; speedup vs baseline: 1.1027x; 1.1027x over previous
//
#include <hip/hip_runtime.h>
#include <hip/hip_bf16.h>
#include <math.h>
#include <stdint.h>

#define N_ATOMS 512
#define NF 64
#define NB 8
#define NBINS 64
#define NSEG 511     // segment nodes 0..510; valid pairs i<j, j>=i+2
#define NTF 8192     // fine m(wr) grid (nearest; bf16; sentinel row = NTF)
#define NSENT 2554   // invalid (dst,src) slots per batch needing the zero-sentinel
#define ETILES2 254  // ceil(P/512) edge tiles per batch (2 edges/thread)

__device__ __forceinline__ float dot3(float ax, float ay, float az,
                                      float bx, float by, float bz) {
    return fmaf(ax, bx, fmaf(ay, by, az * bz));
}

__device__ __forceinline__ uint16_t bf16_bits(float f) {
    union { __hip_bfloat16 h; uint16_t u; } cv;
    cv.h = __float2bfloat16(f);
    return cv.u;
}

// writhe scalar for edge (i,j), i<j — verified (R2..R15 absmax 0.0625).
// pb may point to LDS (generic pointer) — xyz layout [atom][3].
__device__ __forceinline__ float compute_wr(const float* pb, int i, int j) {
    float p0x = pb[3*i+0], p0y = pb[3*i+1], p0z = pb[3*i+2];
    float p1x = pb[3*i+3], p1y = pb[3*i+4], p1z = pb[3*i+5];
    float p2x = pb[3*j+0], p2y = pb[3*j+1], p2z = pb[3*j+2];
    float p3x = pb[3*j+3], p3y = pb[3*j+4], p3z = pb[3*j+5];

    float d0x = p2x-p0x, d0y = p2y-p0y, d0z = p2z-p0z;
    float d1x = p3x-p0x, d1y = p3y-p0y, d1z = p3z-p0z;
    float d2x = p2x-p1x, d2y = p2y-p1y, d2z = p2z-p1z;
    float d3x = p3x-p1x, d3y = p3y-p1y, d3z = p3z-p1z;
    {
        float n0 = rsqrtf(dot3(d0x,d0y,d0z,d0x,d0y,d0z)); d0x*=n0; d0y*=n0; d0z*=n0;
        float n1 = rsqrtf(dot3(d1x,d1y,d1z,d1x,d1y,d1z)); d1x*=n1; d1y*=n1; d1z*=n1;
        float n2 = rsqrtf(dot3(d2x,d2y,d2z,d2x,d2y,d2z)); d2x*=n2; d2y*=n2; d2z*=n2;
        float n3 = rsqrtf(dot3(d3x,d3y,d3z,d3x,d3y,d3z)); d3x*=n3; d3y*=n3; d3z*=n3;
    }
    float c0x = d0y*d1z - d0z*d1y, c0y = d0z*d1x - d0x*d1z, c0z = d0x*d1y - d0y*d1x;
    float c1x = d1y*d3z - d1z*d3y, c1y = d1z*d3x - d1x*d3z, c1z = d1x*d3y - d1y*d3x;
    float c3x = d2y*d0z - d2z*d0y, c3y = d2z*d0x - d2x*d0z, c3z = d2x*d0y - d2y*d0x;
    {
        float n0 = rsqrtf(dot3(c0x,c0y,c0z,c0x,c0y,c0z)); c0x*=n0; c0y*=n0; c0z*=n0;
        float n1 = rsqrtf(dot3(c1x,c1y,c1z,c1x,c1y,c1z)); c1x*=n1; c1y*=n1; c1z*=n1;
        float n3 = rsqrtf(dot3(c3x,c3y,c3z,c3x,c3y,c3z)); c3x*=n3; c3y*=n3; c3z*=n3;
    }
    float t0 = fminf(fmaxf(dot3(c0x,c0y,c0z, c1x,c1y,c1z), -1.f), 1.f);
    float t1 = fminf(fmaxf(dot3(c1x,c1y,c1z, c3x,c3y,c3z), -1.f), 1.f);
    float t3 = fminf(fmaxf(dot3(c3x,c3y,c3z, c0x,c0y,c0z), -1.f), 1.f);
    float omega = asinf(t0) + asinf(t1) + asinf(t3) + 1.5707963267948966f;
    float ex = p3x-p2x, ey = p3y-p2y, ez = p3z-p2z;
    float fx = p1x-p0x, fy = p1y-p0y, fz = p1z-p0z;
    float gx = ey*fz - ez*fy, gy = ez*fx - ex*fz, gz = ex*fy - ey*fx;
    float sgd = dot3(gx,gy,gz, d0x,d0y,d0z);
    float sgn = (sgd > 0.f) ? 1.f : ((sgd < 0.f) ? -1.f : 0.f);
    return omega * sgn * 0.15915494309189535f;
}

// map wr -> pre-shifted nearest table element offset (proven R13..R15)
__device__ __forceinline__ uint32_t wr_to_off(float w) {
    float tf = (w + 1.0f) * ((float)(NTF - 1) * 0.5f);
    tf = fminf(fmaxf(tf, 0.0f), (float)(NTF - 1));
    int t0 = (int)(tf + 0.5f);
    t0 = (t0 > NTF - 1) ? (NTF - 1) : t0;
    return (uint32_t)t0 << 6;
}

// ---------------- launch 1: mega-prepass (R5 structure, proven 108.1) -----------
// block ranges: [0,1024) table build (2 pts/wave) | [+2032) edge writhes
//   (xyz in LDS, 2 edges/thread) | next 80 sentinel fill.
__launch_bounds__(256)
__global__ void prepass(
        const float* __restrict__ xyz, const int* __restrict__ seg,
        const float* __restrict__ W1, const float* __restrict__ b1,
        const float* __restrict__ W2, const float* __restrict__ b2,
        uint16_t* __restrict__ tabh, uint32_t* __restrict__ ta, int P) {
    __shared__ float lds[1536];   // build: 2x lh[4][64]; edge: xyz[b] (6 KB)

    const unsigned bx = blockIdx.x;

    if (bx < NTF / 8) {
        // ------- bf16 fine-table build: wave handles g and g+NTF/2 (ILP x2) -----
        const int widx = threadIdx.x >> 6;
        const int lane = threadIdx.x & 63;
        const int g = bx * 4 + widx;              // 0..4095
        const int g2 = g + NTF / 2;               // 4096..8191

        float tta = ((-1.0f + (2.0f / (float)(NTF - 1)) * (float)g)  + 1.0f) * 31.5f;
        float ttb = ((-1.0f + (2.0f / (float)(NTF - 1)) * (float)g2) + 1.0f) * 31.5f;

        float a0=0.f,a1=0.f,a2=0.f,a3=0.f, e0=0.f,e1=0.f,e2=0.f,e3=0.f;
        #pragma unroll
        for (int k = 0; k < NBINS; k += 4) {
            #pragma unroll
            for (int q = 0; q < 4; ++q) {
                float da = tta - (float)(k + q);
                float db = ttb - (float)(k + q);
                float ra = __expf(-da * da) * 0.8928571428571429f;
                float rb = __expf(-db * db) * 0.8928571428571429f;
                float wv = W1[(k + q) * NF + lane];
                if (q == 0) { a0 = fmaf(ra, wv, a0); e0 = fmaf(rb, wv, e0); }
                if (q == 1) { a1 = fmaf(ra, wv, a1); e1 = fmaf(rb, wv, e1); }
                if (q == 2) { a2 = fmaf(ra, wv, a2); e2 = fmaf(rb, wv, e2); }
                if (q == 3) { a3 = fmaf(ra, wv, a3); e3 = fmaf(rb, wv, e3); }
            }
        }
        float ha = ((a0 + a1) + (a2 + a3)) + b1[lane];
        float hb = ((e0 + e1) + (e2 + e3)) + b1[lane];
        ha = fmaxf(ha, 0.01f * ha);
        hb = fmaxf(hb, 0.01f * hb);
        lds[widx * 64 + lane]       = ha;
        lds[256 + widx * 64 + lane] = hb;
        __syncthreads();

        float m0=0.f,m1=0.f,m2=0.f,m3=0.f, n0=0.f,n1=0.f,n2=0.f,n3=0.f;
        #pragma unroll
        for (int k = 0; k < NF; k += 4) {
            float w0 = W2[(k + 0) * NF + lane];
            float w1v = W2[(k + 1) * NF + lane];
            float w2v = W2[(k + 2) * NF + lane];
            float w3 = W2[(k + 3) * NF + lane];
            m0 = fmaf(lds[widx * 64 + k + 0], w0, m0);
            m1 = fmaf(lds[widx * 64 + k + 1], w1v, m1);
            m2 = fmaf(lds[widx * 64 + k + 2], w2v, m2);
            m3 = fmaf(lds[widx * 64 + k + 3], w3, m3);
            n0 = fmaf(lds[256 + widx * 64 + k + 0], w0, n0);
            n1 = fmaf(lds[256 + widx * 64 + k + 1], w1v, n1);
            n2 = fmaf(lds[256 + widx * 64 + k + 2], w2v, n2);
            n3 = fmaf(lds[256 + widx * 64 + k + 3], w3, n3);
        }
        float ma = ((m0 + m1) + (m2 + m3)) + b2[lane];
        float mb = ((n0 + n1) + (n2 + n3)) + b2[lane];
        tabh[g  * NF + lane] = bf16_bits(ma);
        tabh[g2 * NF + lane] = bf16_bits(mb);
        if (g == 0) tabh[NTF * NF + lane] = 0;     // sentinel zero row
    } else if (bx < NTF / 8 + NB * ETILES2) {
        // ------- edge writhes, xyz[b] in LDS, 2 independent edges/thread --------
        const int rel = bx - NTF / 8;
        const int b = rel / ETILES2;
        const int tile = rel - b * ETILES2;

        const float* xb = xyz + b * (N_ATOMS * 3);
        #pragma unroll
        for (int k = 0; k < 6; ++k)
            lds[k * 256 + threadIdx.x] = xb[k * 256 + threadIdx.x];
        __syncthreads();

        #pragma unroll
        for (int q = 0; q < 2; ++q) {
            const int e = tile * 512 + q * 256 + threadIdx.x;
            if (e < P) {
                int4 sv = ((const int4*)seg)[e];
                const int i = sv.x;
                const int j = sv.z;
                uint32_t u = wr_to_off(compute_wr(lds, i, j));
                ta[(b << 18) + (i << 9) + j] = u;
                ta[(b << 18) + (j << 9) + i] = u;   // mirror (m symmetric)
            }
        }
    } else {
        // ------- sentinel fill --------------------------------------------------
        const int idx = (bx - (NTF / 8 + NB * ETILES2)) * 256 + threadIdx.x;
        if (idx < NB * NSENT) {
            const int b = idx / NSENT;
            const int k = idx - b * NSENT;
            int d, s;
            if      (k < 512)  { d = k;        s = k;     }   // diagonal
            else if (k < 1023) { d = k - 512;  s = d + 1; }   // upper band
            else if (k < 1534) { s = k - 1023; d = s + 1; }   // lower band
            else if (k < 2044) { d = k - 1534; s = NSEG;  }   // col 511 (d<=509)
            else               { s = k - 2044; d = NSEG;  }   // row 511 (s<=509)
            ta[(b << 18) + (d << 9) + s] = (uint32_t)NTF << 6;  // -> zero row
        }
    }
}

// ---------------- launch 2: aggregation v18 — agg15 + preloaded ta + 8-deep -----
// Revert to the PROVEN agg15 shell (R5, 108.1 us: pair-packed gather, LDS-staged
// x, 4 chunk barriers, 2 blocks/CU — R8 proved removing staging/barriers hurts).
// Two scheduling-only changes, numerics identical:
//  (1) ALL 4 per-chunk ta offset vectors preloaded at kernel start (4 coalesced
//      dwords -> VGPRs). Removes the dependent ~200cy L2 load that sat on the
//      critical path right before each barrier (4x per wave).
//  (2) gather batching deepened 4 -> 8 in flight (R3 proved 8-deep batching is
//      the effective depth; +4 VGPRs, still far under the 64/wave budget).
__launch_bounds__(1024, 8)
__global__ void agg18(
        const float* __restrict__ x, const uint32_t* __restrict__ ta,
        const uint16_t* __restrict__ tabh, float* __restrict__ out) {
    __shared__ float xs[16384];   // [buf(2)][half(2)][4096 floats]

    const int tid  = threadIdx.x;
    const int widx = tid >> 6;               // 0..15
    const int lane = tid & 63;
    const int fl   = lane & 31;              // feature pair: features 2fl, 2fl+1
    const int hw   = lane >> 5;              // src parity served by this lane
    const int h    = widx >> 3;              // chunk-half: chunks h*4 .. h*4+3
    const int r    = widx & 7;               // dst row within block
    const int ht   = tid & 511;              // half-local thread id
    const int bid  = blockIdx.x;             // 0..511
    const int b    = bid >> 6;
    const int dst  = ((bid & 63) << 3) + r;  // 0..511

    const float* xb = x + ((size_t)b << 15);
    const uint32_t* tarow = ta + ((size_t)b << 18) + ((size_t)dst << 9);

    // (1) preload this half's 4 chunk offset vectors (coalesced, independent)
    const int tv0 = (int)tarow[((h * 4 + 0) << 6) + lane];
    const int tv1 = (int)tarow[((h * 4 + 1) << 6) + lane];
    const int tv2 = (int)tarow[((h * 4 + 2) << 6) + lane];
    const int tv3 = (int)tarow[((h * 4 + 3) << 6) + lane];

    // prologue: stage this half's first chunk (c = h*4) into buf0
    {
        const float* xsrc = xb + ((h * 4) << 12);
        float* xdst = xs + (h << 12);
        #pragma unroll
        for (int k = 0; k < 8; ++k)
            xdst[k * 512 + ht] = xsrc[k * 512 + ht];
    }

    const int xoffl = (hw << 6) + (fl << 1); // per-lane float offset in chunk
    const int feidx = fl << 1;               // dword elem offset within table row

    float accL = 0.0f, accH = 0.0f;
    #pragma unroll
    for (int p = 0; p < 4; ++p) {
        const int c = h * 4 + p;
        const int tavc = (p == 0) ? tv0 : (p == 1) ? tv1 : (p == 2) ? tv2 : tv3;

        __syncthreads();   // chunk staged; everyone done reading previous buf

        if (p < 3) {
            // stage this half's next chunk into the other buffer
            const float* xsrc = xb + ((c + 1) << 12);
            float* xdst = xs + ((((p + 1) & 1) << 13) + (h << 12));
            #pragma unroll
            for (int k = 0; k < 8; ++k)
                xdst[k * 512 + ht] = xsrc[k * 512 + ht];
        }

        const float* xc = xs + (((p & 1) << 13) + (h << 12)) + xoffl;
        #pragma unroll
        for (int s8 = 0; s8 < 32; s8 += 8) {
            // ---- (2) issue 8 independent pair loads (each covers 2 src rows) ---
            uint32_t mw[8];
            #pragma unroll
            for (int q = 0; q < 8; ++q) {
                const int s = s8 + q;
                const uint32_t o0 =
                    (uint32_t)__builtin_amdgcn_readlane(tavc, 2 * s);
                const uint32_t o1 =
                    (uint32_t)__builtin_amdgcn_readlane(tavc, 2 * s + 1);
                const uint32_t osel = hw ? o1 : o0;        // per-half row select
                mw[q] = *(const uint32_t*)(tabh + osel + feidx);
            }
            // ---- consume: unpack bf16 pair + x pair + 2 fma --------------------
            #pragma unroll
            for (int q = 0; q < 8; ++q) {
                const int s = s8 + q;
                const float mlo = __uint_as_float(mw[q] << 16);
                const float mhi = __uint_as_float(mw[q] & 0xffff0000u);
                const float2 xv = *(const float2*)(xc + (s << 7));
                accL = fmaf(mlo, xv.x, accL);
                accH = fmaf(mhi, xv.y, accH);
            }
        }
    }
    // sum over src parity (the two half-waves of this wave)
    accL += __shfl_xor(accL, 32);
    accH += __shfl_xor(accH, 32);

    // combine chunk-halves: h=1 publishes partial, h=0 adds and stores
    __syncthreads();
    if (h == 1 && hw == 0) {
        xs[(r << 6) + feidx]     = accL;
        xs[(r << 6) + feidx + 1] = accH;
    }
    __syncthreads();
    if (h == 0 && hw == 0) {
        const float2 prev = *(const float2*)&xs[(r << 6) + feidx];
        const float2 xv   = *(const float2*)(xb + (dst << 6) + feidx);
        float2 res;
        res.x = xv.x + accL + prev.x;
        res.y = xv.y + accH + prev.y;
        *(float2*)(out + ((size_t)b << 15) + (dst << 6) + feidx) = res;
    }
}

// ---------------- fallback path (ws too small): R2 atomic kernel (proven) -------

__global__ void init_out_kernel(const float* __restrict__ x, float* __restrict__ out, int n) {
    int idx = blockIdx.x * blockDim.x + threadIdx.x;
    if (idx < n) out[idx] = x[idx];
}

__device__ __forceinline__ void compute_m(
        const float* __restrict__ pb, int i, int j,
        const float* __restrict__ W1, const float* __restrict__ b1,
        const float* __restrict__ W2, const float* __restrict__ b2,
        float* __restrict__ mout) {
    float wr = compute_wr(pb, i, j);
    float acc_[NBINS];
    {
        float tt = (wr + 1.0f) * 31.5f;
        #pragma unroll
        for (int k = 0; k < NBINS; ++k) {
            float d = tt - (float)k;
            acc_[k] = __expf(-d * d) * 0.8928571428571429f;
        }
    }
    float h_[NF];
    #pragma unroll
    for (int f = 0; f < NF; ++f) h_[f] = b1[f];
    #pragma unroll
    for (int k = 0; k < NBINS; ++k) {
        float r = acc_[k];
        #pragma unroll
        for (int f = 0; f < NF; ++f) h_[f] = fmaf(r, W1[k * NF + f], h_[f]);
    }
    #pragma unroll
    for (int f = 0; f < NF; ++f) h_[f] = fmaxf(h_[f], 0.01f * h_[f]);
    #pragma unroll
    for (int f = 0; f < NF; ++f) acc_[f] = b2[f];
    #pragma unroll
    for (int k = 0; k < NF; ++k) {
        float hk = h_[k];
        #pragma unroll
        for (int f = 0; f < NF; ++f) acc_[f] = fmaf(hk, W2[k * NF + f], acc_[f]);
    }
    #pragma unroll
    for (int f = 0; f < NF; ++f) mout[f] = acc_[f];
}

__launch_bounds__(256, 2)
__global__ void writhe_msg_atomic_kernel(
        const float* __restrict__ x, const float* __restrict__ xyz,
        const int* __restrict__ seg,
        const float* __restrict__ W1, const float* __restrict__ b1,
        const float* __restrict__ W2, const float* __restrict__ b2,
        float* __restrict__ out, int P, int n_tiles) {
    __shared__ __hip_bfloat16 lds_m[4][64 * 65];
    __shared__ int lds_i[4][64];
    __shared__ int lds_j[4][64];

    const int widx = threadIdx.x >> 6;
    const int lane = threadIdx.x & 63;
    const int wave_g = blockIdx.x * 4 + widx;
    const int b = wave_g / n_tiles;
    const int tile = wave_g - b * n_tiles;
    const int bc = (b < NB) ? b : 0;
    const int e = tile * 64 + lane;
    const bool valid = (b < NB) && (e < P);

    int4 sv = valid ? ((const int4*)seg)[e] : make_int4(0, 1, 2, 3);
    const int i = sv.x;
    const int j = sv.z;

    float m[NF];
    compute_m(xyz + bc * (N_ATOMS * 3), i, j, W1, b1, W2, b2, m);

    const float scale = valid ? 1.0f : 0.0f;
    #pragma unroll
    for (int f = 0; f < NF; ++f)
        lds_m[widx][lane * 65 + f] = __float2bfloat16(m[f] * scale);
    lds_i[widx][lane] = i;
    lds_j[widx][lane] = j;
    __syncthreads();

    const float* xb = x + bc * (N_ATOMS * NF);
    float* ob = out + bc * (N_ATOMS * NF);
    int cur_i = lds_i[widx][0];
    float acc_i = 0.0f;
    for (int ee = 0; ee < 64; ++ee) {
        int ie = lds_i[widx][ee];
        int je = lds_j[widx][ee];
        float mv = __bfloat162float(lds_m[widx][ee * 65 + lane]);
        float xi = xb[ie * NF + lane];
        float xj = xb[je * NF + lane];
        atomicAdd(&ob[je * NF + lane], mv * xi);
        if (ie != cur_i) {
            atomicAdd(&ob[cur_i * NF + lane], acc_i);
            acc_i = 0.0f;
            cur_i = ie;
        }
        acc_i = fmaf(mv, xj, acc_i);
    }
    atomicAdd(&ob[cur_i * NF + lane], acc_i);
}

extern "C" void kernel_launch(void* const* d_in, const int* in_sizes, int n_in,
                              void* d_out, int out_size, void* d_ws, size_t ws_size,
                              hipStream_t stream) {
    const float* x   = (const float*)d_in[0];
    const float* xyz = (const float*)d_in[1];
    const int*   seg = (const int*)d_in[2];
    const float* W1  = (const float*)d_in[3];
    const float* b1  = (const float*)d_in[4];
    const float* W2  = (const float*)d_in[5];
    const float* b2  = (const float*)d_in[6];
    float* out = (float*)d_out;

    const int P = in_sizes[2] / 4;              // 129795 edges
    const int n_tiles = (P + 63) / 64;          // 2029

    const size_t tabh_bytes = (size_t)(NTF + 1) * NF * sizeof(uint16_t);         // 1.05 MB
    const size_t ta_bytes   = (size_t)NB * N_ATOMS * N_ATOMS * sizeof(uint32_t); // 8 MB
    const size_t need_ws = tabh_bytes + ta_bytes;

    if (ws_size >= need_ws && P <= ETILES2 * 512) {
        uint16_t* tabh = (uint16_t*)d_ws;
        uint32_t* ta   = (uint32_t*)((char*)d_ws + tabh_bytes);

        const int nsent_blocks = (NB * NSENT + 255) / 256;            // 80
        const int total_blocks = NTF / 8 + NB * ETILES2 + nsent_blocks;
        hipLaunchKernelGGL(prepass, dim3(total_blocks), dim3(256), 0, stream,
                           xyz, seg, W1, b1, W2, b2, tabh, ta, P);

        hipLaunchKernelGGL(agg18, dim3(NB * 64), dim3(1024), 0, stream,
                           x, ta, tabh, out);
    } else {
        const int n = out_size;
        hipLaunchKernelGGL(init_out_kernel, dim3((n + 255) / 256), dim3(256), 0, stream,
                           x, out, n);
        const int total_waves = NB * n_tiles;
        const int blocks = (total_waves + 3) / 4;
        hipLaunchKernelGGL(writhe_msg_atomic_kernel, dim3(blocks), dim3(256), 0, stream,
                           x, xyz, seg, W1, b1, W2, b2, out, P, n_tiles);
    }
}